// Round 5
// baseline (146.702 us; speedup 1.0000x reference)
//
#include <hip/hip_runtime.h>
#include <cstdint>
#include <cstddef>

typedef __fp16 half8 __attribute__((ext_vector_type(8)));
typedef float  f32x4 __attribute__((ext_vector_type(4)));

#define BATCH 8192
#define INDIM 2048
#define OUTD  512
#define NC    256      // 16 trees * 16 (15 nodes + 1 zero pad)
#define BM    32       // rows per block -> 256 blocks = 1/CU
#define BK    256      // GEMM1 k-chunk (big: BW-dominated phases)
#define NCH   (INDIM / BK)   // 8 chunks

__device__ __forceinline__ half8 cvt8(float4 a, float4 b) {
  half8 h;
  h[0] = (__fp16)a.x; h[1] = (__fp16)a.y; h[2] = (__fp16)a.z; h[3] = (__fp16)a.w;
  h[4] = (__fp16)b.x; h[5] = (__fp16)b.y; h[6] = (__fp16)b.z; h[7] = (__fp16)b.w;
  return h;
}

// ---- prep: WrT[16t+n][k] fp16 (n==15 zero pad). Coalesced read + LDS transpose. ----
__global__ __launch_bounds__(256)
void kprepW(const float* __restrict__ nw, __fp16* __restrict__ WrT) {
  __shared__ float Ls[128][16];
  const int tid = threadIdx.x;
  const int t  = blockIdx.x >> 4;
  const int k0 = (blockIdx.x & 15) * 128;
  const float* base = nw + ((size_t)t * INDIM + k0) * 15;
  #pragma unroll
  for (int i = 0; i < 8; i++) {
    int fl = tid + 256 * i;            // 0..2047, need < 1920
    if (fl < 1920) {
      float v = base[fl];
      int kk = (int)(((unsigned)fl * 8739u) >> 17);   // fl / 15
      int n  = fl - 15 * kk;
      Ls[kk][n] = v;
    }
  }
  __syncthreads();
  const int n  = tid >> 4;             // 0..15
  const int kc = tid & 15;             // 8-wide k chunk
  half8 h = {};
  if (n < 15) {
    #pragma unroll
    for (int j = 0; j < 8; j++) h[j] = (__fp16)Ls[kc * 8 + j][n];
  }
  *(half8*)(WrT + (size_t)(16 * t + n) * INDIM + k0 + kc * 8) = h;
}

// ---- prep: LWrT[o][16t+l] fp16. Coalesced read + LDS transpose. 64 blocks. ----
__global__ __launch_bounds__(256)
void kprepL(const float* __restrict__ lw, __fp16* __restrict__ LWrT) {
  __shared__ float Ls[128][17];
  const int tid = threadIdx.x;
  const int t  = blockIdx.x >> 2;           // 0..15
  const int o0 = (blockIdx.x & 3) * 128;    // 0..384
  const float* base = lw + ((size_t)t * OUTD + o0) * 16;
  #pragma unroll
  for (int i = 0; i < 8; i++) {
    int fl = tid + 256 * i;                 // 0..2047 = 128 o x 16 l, coalesced
    Ls[fl >> 4][fl & 15] = base[fl];
  }
  __syncthreads();
  const int ol = tid >> 1;                  // 0..127
  const int h  = tid & 1;                   // half
  half8 v;
  #pragma unroll
  for (int j = 0; j < 8; j++) v[j] = (__fp16)Ls[ol][8 * h + j];
  *(half8*)(LWrT + (size_t)(o0 + ol) * NC + 16 * t + 8 * h) = v;
}

// ---- fused: GEMM1 (MFMA fp16, chunk-ahead prefetch) -> gates -> probs -> GEMM2 ----
__global__ __launch_bounds__(512, 1)
void kfused(const float* __restrict__ x, const __fp16* __restrict__ WrT,
            const __fp16* __restrict__ LWrT, float* __restrict__ out) {
  __shared__ char   uni[BM * NC * 4];          // 32 KB: Xs dbuf (2 x 16 KB) | As (32 KB)
  __shared__ __fp16 Ps[BM * NC];               // 16 KB
  __fp16* Xs = (__fp16*)uni;                   // elem (r*BK + k) ^ ((r&7)<<3), per buffer
  float*  As = (float*)uni;

  const int tid  = threadIdx.x;
  const int lane = tid & 63;
  const int wv   = tid >> 6;       // 0..7
  const int l15  = lane & 15;
  const int lg   = lane >> 4;      // 0..3
  const int r0   = blockIdx.x * BM;
  const int sr   = tid >> 4;       // staging row 0..31
  const int seg  = tid & 15;       // 16-float segment within BK

  const float*  xrow  = x + (size_t)(r0 + sr) * INDIM + seg * 16;
  const __fp16* wbase = WrT + (size_t)(32 * wv + l15) * INDIM + lg * 8;

  const int sE0 = (sr * BK + seg * 16)     ^ ((sr & 7) << 3);
  const int sE1 = (sr * BK + seg * 16 + 8) ^ ((sr & 7) << 3);

  f32x4 acc1[2][2] = {};
  float4 px[4];

  // prologue: stage chunk 0
  {
    const float* p = xrow;
    float4 a0 = *(const float4*)(p);      float4 a1 = *(const float4*)(p + 4);
    float4 a2 = *(const float4*)(p + 8);  float4 a3 = *(const float4*)(p + 12);
    *(half8*)&Xs[sE0] = cvt8(a0, a1);
    *(half8*)&Xs[sE1] = cvt8(a2, a3);
  }
  __syncthreads();

  #pragma unroll 1
  for (int ch = 0; ch < NCH; ++ch) {
    const int cur = ch & 1;
    const bool more = (ch + 1 < NCH);
    // issue next X chunk (HBM) — consumed only at STX after compute
    if (more) {
      const float* p = xrow + (ch + 1) * BK;
      px[0] = *(const float4*)(p);      px[1] = *(const float4*)(p + 4);
      px[2] = *(const float4*)(p + 8);  px[3] = *(const float4*)(p + 12);
    }
    // compute chunk ch: B direct L2->reg, A frags from LDS
    #pragma unroll
    for (int ks = 0; ks < BK / 32; ks++) {
      half8 bf0 = *(const half8*)(wbase + (size_t)0  * INDIM + ch * BK + ks * 32);
      half8 bf1 = *(const half8*)(wbase + (size_t)16 * INDIM + ch * BK + ks * 32);
      half8 af[2];
      #pragma unroll
      for (int mt = 0; mt < 2; mt++) {
        const int r = l15 + 16 * mt;
        const int e = (r * BK + ks * 32 + lg * 8) ^ ((r & 7) << 3);
        af[mt] = *(const half8*)&Xs[cur * (BM * BK) + e];
      }
      acc1[0][0] = __builtin_amdgcn_mfma_f32_16x16x32_f16(af[0], bf0, acc1[0][0], 0, 0, 0);
      acc1[0][1] = __builtin_amdgcn_mfma_f32_16x16x32_f16(af[0], bf1, acc1[0][1], 0, 0, 0);
      acc1[1][0] = __builtin_amdgcn_mfma_f32_16x16x32_f16(af[1], bf0, acc1[1][0], 0, 0, 0);
      acc1[1][1] = __builtin_amdgcn_mfma_f32_16x16x32_f16(af[1], bf1, acc1[1][1], 0, 0, 0);
    }
    // stage chunk ch+1 into the other buffer (chunk-ch readers of it finished last iter)
    if (more) {
      const int off = (cur ^ 1) * (BM * BK);
      *(half8*)&Xs[off + sE0] = cvt8(px[0], px[1]);
      *(half8*)&Xs[off + sE1] = cvt8(px[2], px[3]);
    }
    __syncthreads();
  }

  // write A tile: C layout col=lane&15, row=4*(lane>>4)+reg  [m89-verified]
  #pragma unroll
  for (int mt = 0; mt < 2; mt++)
    #pragma unroll
    for (int nt = 0; nt < 2; nt++)
      #pragma unroll
      for (int i = 0; i < 4; i++)
        As[(16 * mt + 4 * lg + i) * NC + 32 * wv + 16 * nt + l15] = acc1[mt][nt][i];
  __syncthreads();

  // gates + leaf probs: one thread per (row, tree)
  {
    const int row = tid >> 4, tr = tid & 15;
    float av[16];
    #pragma unroll
    for (int q = 0; q < 4; q++) {
      f32x4 v = *(const f32x4*)&As[row * NC + tr * 16 + 4 * q];
      av[4 * q + 0] = v[0]; av[4 * q + 1] = v[1];
      av[4 * q + 2] = v[2]; av[4 * q + 3] = v[3];
    }
    float sg[15];
    #pragma unroll
    for (int m = 0; m < 15; m++) {
      float t = fminf(fmaxf(av[m] + 0.5f, 0.f), 1.f);   // SMOOTH_STEP_PARAM = 1
      sg[m] = t * t * (3.f - 2.f * t);
    }
    float p[16];
    #pragma unroll
    for (int l = 0; l < 16; l++) {
      float pr = 1.f; int node = 0;
      #pragma unroll
      for (int L = 0; L < 4; L++) {
        int bit = (l >> (3 - L)) & 1;  // 0 = left (s), 1 = right (1-s)
        pr *= bit ? (1.f - sg[node]) : sg[node];
        node = 2 * node + 1 + bit;
      }
      p[l] = pr;
    }
    half8 h0, h1;
    #pragma unroll
    for (int j = 0; j < 8; j++) { h0[j] = (__fp16)p[j]; h1[j] = (__fp16)p[8 + j]; }
    const int base = row * NC + tr * 16;
    const int swz  = (row & 7) << 3;
    *(half8*)&Ps[(base) ^ swz]     = h0;
    *(half8*)&Ps[(base + 8) ^ swz] = h1;
  }
  __syncthreads();

  // GEMM2: out[32][512] = P[32][256] * LWrT^T ; B direct from L2 (reuse == 1)
  f32x4 acc2[2][4] = {};
  const __fp16* lbase = LWrT + (size_t)(64 * wv + l15) * NC + lg * 8;
  #pragma unroll
  for (int kc = 0; kc < 2; kc++) {
    half8 bf2[4][4];
    #pragma unroll
    for (int nt = 0; nt < 4; nt++)
      #pragma unroll
      for (int ks = 0; ks < 4; ks++)
        bf2[nt][ks] = *(const half8*)(lbase + (size_t)nt * 16 * NC + kc * 128 + ks * 32);
    #pragma unroll
    for (int ks = 0; ks < 4; ks++) {
      half8 af[2];
      #pragma unroll
      for (int mt = 0; mt < 2; mt++) {
        const int r = l15 + 16 * mt;
        const int e = (r * NC + kc * 128 + ks * 32 + lg * 8) ^ ((r & 7) << 3);
        af[mt] = *(const half8*)&Ps[e];
      }
      #pragma unroll
      for (int mt = 0; mt < 2; mt++)
        #pragma unroll
        for (int nt = 0; nt < 4; nt++)
          acc2[mt][nt] = __builtin_amdgcn_mfma_f32_16x16x32_f16(af[mt], bf2[nt][ks], acc2[mt][nt], 0, 0, 0);
    }
  }
  #pragma unroll
  for (int mt = 0; mt < 2; mt++)
    #pragma unroll
    for (int nt = 0; nt < 4; nt++)
      #pragma unroll
      for (int i = 0; i < 4; i++)
        out[(size_t)(r0 + 16 * mt + 4 * lg + i) * OUTD + 64 * wv + 16 * nt + l15] = acc2[mt][nt][i];
}

extern "C" void kernel_launch(void* const* d_in, const int* in_sizes, int n_in,
                              void* d_out, int out_size, void* d_ws, size_t ws_size,
                              hipStream_t stream) {
  const float* x  = (const float*)d_in[0];
  const float* nw = (const float*)d_in[1];
  const float* lw = (const float*)d_in[2];
  float* out = (float*)d_out;

  __fp16* WrT  = (__fp16*)d_ws;                                   // 1 MB
  __fp16* LWrT = (__fp16*)((char*)d_ws + (size_t)NC * INDIM * 2); // 256 KB

  hipLaunchKernelGGL(kprepW, dim3(256), dim3(256), 0, stream, nw, WrT);
  hipLaunchKernelGGL(kprepL, dim3(64),  dim3(256), 0, stream, lw, LWrT);
  hipLaunchKernelGGL(kfused, dim3(BATCH / BM), dim3(512), 0, stream, x, WrT, LWrT, out);
}